// Round 25
// baseline (125.267 us; speedup 1.0000x reference)
//
#include <hip/hip_runtime.h>
#include <math.h>

// Fused Actor network via single-term fp16 MFMA. Round 25: r24 + waves_per_eu(5).
// r24 completed the model: min=6 -> CP residency 3 blocks/CU (occ 60.5%, confirmed)
// AND budget 40 regs; measured demand of the slimmed kernel = ~48-51 (spill reloads
// ~48MB FETCH = ~11 regs/thread). Allocator law: budget ~= 512/(2*min).
// min=5 -> budget ~51 = exactly the demand -> first no-spill 3-blocks/CU config.
// Single change vs r24. Block = 32 samples, 512 threads = 8 waves, LDS 41,216 B.
// E1/E2 expert-sequential RMW passes (8 accs), asm MFMA "+v" (no AGPR granule),
// hazard fences (proven r20-r24), bias-fold, f32 coeffs, fast tanh, depth-1 prefetch.
// Weights pre-tiled in d_ws (per-wave 1KB bursts). LDS XOR-swizzle byte^=(row&7)<<4.

typedef __attribute__((ext_vector_type(8))) _Float16 half8;
typedef __attribute__((ext_vector_type(4))) _Float16 half4;
typedef __attribute__((ext_vector_type(4))) float    f32x4;

__device__ __forceinline__ f32x4 mfma16(half8 a, half8 b, f32x4 c) {
    // s_nop 1 guards VALU-write -> MFMA-read; "v" = VGPR class (no AGPR granule)
    asm("s_nop 1\n\tv_mfma_f32_16x16x32_f16 %0, %1, %2, %0" : "+v"(c) : "v"(a), "v"(b));
    return c;
}
#define MFMA16(a, b, c) mfma16((a), (b), (c))
#define MFMA_FENCE() do {                                    \
    __builtin_amdgcn_sched_barrier(0);                       \
    asm volatile("s_nop 7\n\ts_nop 7" ::: );                 \
    __builtin_amdgcn_sched_barrier(0);                       \
} while (0)

#define SWZ(row) (((row) & 7) << 4)

#define MT 32
#define T  512

// ---- LDS byte offsets (total 41,216 B) ----
// S  [0, 24576): 32 rows x 384 f16 (stride 768B); col376 = 1.0 (bias), 377..383 = 0.
//    Dead after E1 -> first 8KB reused as E2 partial buffer P2 (stride 256B).
// G1 [24576, 32768): 32x128 f16 (stride 256B)
// G2 [32768, 40960): 32x128 f16
// H1 [24576, 40960): 32x256 f16 (stride 512B), overlays G1+G2 (dead after A3)
// H2 [24576, 32768): 32x128 f16, overlays H1 rows 0..15 (barrier before write in E2)
// CF [40960, 41216): 32 x (c0,c1) f32
#define S_B      0
#define P2_B     0
#define G1_B     24576
#define G2_B     32768
#define H1_B     24576
#define H2_B     24576
#define CF_B     40960
#define LDS_BYTES 41216

// ---- ws half-element offsets; tiled: tile(n0,kc) at ((n0*KC+kc)*512), [lane][8] ----
#define WS_W1 0        /* bw1: N0=8,  KC=12 (k=376 holds bb1) */
#define WS_W2 49152    /* bw2: N0=8,  KC=4 */
#define WS_E1 65536    /* ew1: N0=32, KC=12 (k=376 holds eb1) */
#define WS_E2 262144   /* ew2: N0=16, KC=8 */
#define WS_EM 327680   /* ewm: N0=4,  KC=4 (2 experts x 32 rows padded) */
#define WS_HALFS 335872
#define WS_BYTES 671744

__device__ __forceinline__ half8 cvt8(const float* __restrict__ p) {
    const float4 a = *reinterpret_cast<const float4*>(p);
    const float4 b = *reinterpret_cast<const float4*>(p + 4);
    half8 r;
    r[0] = (_Float16)a.x; r[1] = (_Float16)a.y; r[2] = (_Float16)a.z; r[3] = (_Float16)a.w;
    r[4] = (_Float16)b.x; r[5] = (_Float16)b.y; r[6] = (_Float16)b.z; r[7] = (_Float16)b.w;
    return r;
}

// ================= prep kernel: fp32 weights -> fp16 B-fragment tiles in ws =================
__global__ __launch_bounds__(256)
void prep_weights(const float* __restrict__ bw1, const float* __restrict__ bb1,
                  const float* __restrict__ bw2,
                  const float* __restrict__ ew1, const float* __restrict__ eb1,
                  const float* __restrict__ ew2,
                  const float* __restrict__ ewm, _Float16* __restrict__ wsw)
{
    const int i = blockIdx.x * 256 + threadIdx.x;
    if (i >= WS_HALFS) return;
    int sec; const float* W; const float* Bv; int N, K, KC, j0;
    if      (i < 49152)  { sec = 0; W = bw1; Bv = bb1;     N = 128; K = 376; KC = 12; j0 = i - WS_W1; }
    else if (i < 65536)  { sec = 1; W = bw2; Bv = nullptr; N = 128; K = 128; KC = 4;  j0 = i - WS_W2; }
    else if (i < 262144) { sec = 2; W = ew1; Bv = eb1;     N = 512; K = 376; KC = 12; j0 = i - WS_E1; }
    else if (i < 327680) { sec = 3; W = ew2; Bv = nullptr; N = 256; K = 256; KC = 8;  j0 = i - WS_E2; }
    else                 { sec = 4; W = ewm; Bv = nullptr; N = 34;  K = 128; KC = 4;  j0 = i - WS_EM; }
    const int tile = j0 >> 9;
    const int rem  = j0 & 511;
    const int l    = rem >> 3;
    const int jj   = rem & 7;
    const int n0   = tile / KC, kc = tile - n0 * KC;
    const int n = n0 * 16 + (l & 15);
    const int k = kc * 32 + (l >> 4) * 8 + jj;
    float v = 0.f;
    if (sec == 4) {
        const int e = n >> 5, a = n & 31;
        if (a < 17 && k < K) v = ewm[(e * 17 + a) * K + k];
    } else if (n < N) {
        if (k < K)             v = W[n * K + k];
        else if (k == K && Bv) v = Bv[n];
    }
    wsw[i] = (_Float16)v;
}

// ================= fused actor kernel =================
template <bool USE_WS>
__global__ __launch_bounds__(512)
__attribute__((amdgpu_waves_per_eu(5)))
void actor_kernel(const float* __restrict__ states,
                  const float* __restrict__ bw1, const float* __restrict__ bb1,
                  const float* __restrict__ bw2, const float* __restrict__ bb2,
                  const float* __restrict__ bwo, const float* __restrict__ bbo,
                  const float* __restrict__ ew1, const float* __restrict__ eb1,
                  const float* __restrict__ ew2, const float* __restrict__ eb2,
                  const float* __restrict__ ewm, const float* __restrict__ ebm,
                  const _Float16* __restrict__ wsw,
                  float* __restrict__ out)
{
    extern __shared__ char smc[];
    const int t    = threadIdx.x;
    const int l    = t & 63;
    const int l15  = l & 15;
    const int kgrp = l >> 4;
    const int kg16 = kgrp * 16;
    const int wv   = __builtin_amdgcn_readfirstlane(t >> 6);
    const int base = blockIdx.x * MT;
    const int lB   = l * 8;

    const half8 zf = {0,0,0,0,0,0,0,0};

    // ---------- stage ----------
    {
        const float4* src = reinterpret_cast<const float4*>(states + (long)base * 376);
        for (int q = t; q < MT * 94; q += T) {
            const int r  = q / 94;
            const int c4 = q - r * 94;
            const float4 v = src[q];
            half4 h;
            h[0] = (_Float16)v.x; h[1] = (_Float16)v.y;
            h[2] = (_Float16)v.z; h[3] = (_Float16)v.w;
            *(half4*)(smc + S_B + ((r * 768 + c4 * 8) ^ SWZ(r))) = h;
        }
        if (t < MT) {
            const int off = (t * 768 + 752) ^ SWZ(t);
            *(ushort4*)(smc + S_B + off)     = make_ushort4(0x3C00u, 0, 0, 0);
            *(ushort4*)(smc + S_B + off + 8) = make_ushort4(0, 0, 0, 0);
        }
    }
    __syncthreads();

    // ---------- A1: G1 = relu(S @ bw1^T [+bb1 via pad])  M=32 N=128 K=384 ----------
    {
        f32x4 acc[2] = {{0,0,0,0},{0,0,0,0}};
        const int col = wv * 16 + l15;
        auto ldW = [&](int kc) -> half8 {
            if constexpr (USE_WS) return *(const half8*)(wsw + WS_W1 + (wv * 12 + kc) * 512 + lB);
            else {
                const int g = kc * 4 + kgrp;
                if (g < 47) return cvt8(bw1 + col * 376 + g * 8);
                half8 rr = zf; rr[0] = (_Float16)bb1[col]; return rr;
            }
        };
        half8 bf = ldW(0);
        #pragma unroll
        for (int kc = 0; kc < 12; ++kc) {
            const half8 cur = bf;
            if (kc < 11) bf = ldW(kc + 1);
            const int koff = kc * 64 + kg16;
            #pragma unroll
            for (int mt = 0; mt < 2; ++mt) {
                const int row = mt * 16 + l15;
                const half8 af = *(const half8*)(smc + S_B + ((row * 768 + koff) ^ SWZ(row)));
                acc[mt] = MFMA16(af, cur, acc[mt]);
            }
        }
        MFMA_FENCE();
        #pragma unroll
        for (int mt = 0; mt < 2; ++mt) {
            #pragma unroll
            for (int j = 0; j < 4; ++j) {
                const int row = mt * 16 + kgrp * 4 + j;
                const float v = fmaxf(acc[mt][j], 0.f);   // bias in acc
                *(_Float16*)(smc + G1_B + ((row * 256 + col * 2) ^ SWZ(row))) = (_Float16)v;
            }
        }
    }
    __syncthreads();

    // ---------- A2: G2 = relu(G1 @ bw2^T + bb2)  M=32 N=128 K=128 ----------
    {
        f32x4 acc[2] = {{0,0,0,0},{0,0,0,0}};
        const int col = wv * 16 + l15;
        auto ldW = [&](int kc) -> half8 {
            if constexpr (USE_WS) return *(const half8*)(wsw + WS_W2 + (wv * 4 + kc) * 512 + lB);
            else                  return cvt8(bw2 + col * 128 + (kc * 4 + kgrp) * 8);
        };
        half8 bf = ldW(0);
        #pragma unroll
        for (int kc = 0; kc < 4; ++kc) {
            const half8 cur = bf;
            if (kc < 3) bf = ldW(kc + 1);
            const int koff = kc * 64 + kg16;
            #pragma unroll
            for (int mt = 0; mt < 2; ++mt) {
                const int row = mt * 16 + l15;
                const half8 af = *(const half8*)(smc + G1_B + ((row * 256 + koff) ^ SWZ(row)));
                acc[mt] = MFMA16(af, cur, acc[mt]);
            }
        }
        MFMA_FENCE();
        const float bias = bb2[col];
        #pragma unroll
        for (int mt = 0; mt < 2; ++mt) {
            #pragma unroll
            for (int j = 0; j < 4; ++j) {
                const int row = mt * 16 + kgrp * 4 + j;
                const float v = fmaxf(acc[mt][j] + bias, 0.f);
                *(_Float16*)(smc + G2_B + ((row * 256 + col * 2) ^ SWZ(row))) = (_Float16)v;
            }
        }
    }
    __syncthreads();

    // ---------- A3: softmax coeffs -> f32 (c0,c1) in CF ----------
    {
        const int s     = t >> 4;
        const int r     = t & 15;
        const int e     = r & 1;
        const int chunk = r >> 1;
        float z = 0.f;
        const float* wo = bwo + e * 128 + chunk * 16;
        #pragma unroll
        for (int q = 0; q < 2; ++q) {
            const half8 hv = *(const half8*)(smc + G2_B + ((s * 256 + chunk * 32 + q * 16) ^ SWZ(s)));
            const float4 w0 = *(const float4*)(wo + q * 8);
            const float4 w1 = *(const float4*)(wo + q * 8 + 4);
            z = fmaf((float)hv[0], w0.x, z); z = fmaf((float)hv[1], w0.y, z);
            z = fmaf((float)hv[2], w0.z, z); z = fmaf((float)hv[3], w0.w, z);
            z = fmaf((float)hv[4], w1.x, z); z = fmaf((float)hv[5], w1.y, z);
            z = fmaf((float)hv[6], w1.z, z); z = fmaf((float)hv[7], w1.w, z);
        }
        z += __shfl_xor(z, 2, 64);
        z += __shfl_xor(z, 4, 64);
        z += __shfl_xor(z, 8, 64);
        z += bbo[e];
        const float zo = __shfl_xor(z, 1, 64);
        if (r < 2) {
            const float m = fmaxf(z, zo);
            const float ea = __expf(z - m), eb = __expf(zo - m);
            *(float*)(smc + CF_B + s * 8 + e * 4) = ea / (ea + eb);
        }
    }
    __syncthreads();

    // ---------- E1: H1 = relu(c0*(S@ew1_0^T) + c1*(S@ew1_1^T)) [bias via pad] ----------
    // 4 expert-sequential passes; ex0 stores fp16 partial (pre-relu) in H1, ex1 RMWs.
    #pragma unroll 1
    for (int p = 0; p < 2; ++p) {
        #pragma unroll 1
        for (int ex = 0; ex < 2; ++ex) {
            f32x4 acc[2] = {{0,0,0,0},{0,0,0,0}};
            auto ldE1 = [&](int kc) -> half8 {
                if constexpr (USE_WS) {
                    const int n0 = wv * 2 + p + ex * 16;
                    return *(const half8*)(wsw + WS_E1 + (n0 * 12 + kc) * 512 + lB);
                } else {
                    const int g = kc * 4 + kgrp;
                    const int wr = wv * 32 + p * 16 + l15 + ex * 256;
                    if (g < 47) return cvt8(ew1 + wr * 376 + g * 8);
                    half8 rr = zf; rr[0] = (_Float16)eb1[wr]; return rr;
                }
            };
            half8 bf = ldE1(0);
            #pragma unroll
            for (int kc = 0; kc < 12; ++kc) {
                const half8 cur = bf;
                if (kc < 11) bf = ldE1(kc + 1);
                const int koff = kc * 64 + kg16;
                #pragma unroll
                for (int mt = 0; mt < 2; ++mt) {
                    const int row = mt * 16 + l15;
                    const half8 af = *(const half8*)(smc + S_B + ((row * 768 + koff) ^ SWZ(row)));
                    acc[mt] = MFMA16(af, cur, acc[mt]);
                }
            }
            MFMA_FENCE();
            const int col = wv * 32 + p * 16 + l15;
            #pragma unroll
            for (int mt = 0; mt < 2; ++mt) {
                #pragma unroll
                for (int j = 0; j < 4; ++j) {
                    const int row = mt * 16 + kgrp * 4 + j;
                    const float2 cc = *(const float2*)(smc + CF_B + row * 8);
                    _Float16* hp = (_Float16*)(smc + H1_B + ((row * 512 + col * 2) ^ SWZ(row)));
                    if (ex == 0) {
                        *hp = (_Float16)(cc.x * acc[mt][j]);                  // partial, pre-relu
                    } else {
                        const float v = (float)*hp + cc.y * acc[mt][j];
                        *hp = (_Float16)fmaxf(v, 0.f);
                    }
                }
            }
        }
    }
    __syncthreads();

    // ---------- E2: H2 = relu(c0*(H1@ew2_0^T+b0) + c1*(H1@ew2_1^T+b1)) ----------
    {
        const int col = wv * 16 + l15;
        auto ldE2 = [&](int kc, int ex) -> half8 {
            if constexpr (USE_WS) {
                return *(const half8*)(wsw + WS_E2 + ((wv + ex * 8) * 8 + kc) * 512 + lB);
            } else {
                const int g = kc * 4 + kgrp;
                return cvt8(ew2 + (col + ex * 128) * 256 + g * 8);
            }
        };
        // ---- pass ex = 0 ----
        {
            f32x4 acc[2] = {{0,0,0,0},{0,0,0,0}};
            half8 bf = ldE2(0, 0);
            #pragma unroll
            for (int kc = 0; kc < 8; ++kc) {
                const half8 cur = bf;
                if (kc < 7) bf = ldE2(kc + 1, 0);
                const int koff = kc * 64 + kg16;
                #pragma unroll
                for (int mt = 0; mt < 2; ++mt) {
                    const int row = mt * 16 + l15;
                    const half8 af = *(const half8*)(smc + H1_B + ((row * 512 + koff) ^ SWZ(row)));
                    acc[mt] = MFMA16(af, cur, acc[mt]);
                }
            }
            MFMA_FENCE();
            const float b0s = eb2[col];
            #pragma unroll
            for (int mt = 0; mt < 2; ++mt) {
                #pragma unroll
                for (int j = 0; j < 4; ++j) {
                    const int row = mt * 16 + kgrp * 4 + j;
                    const float2 cc = *(const float2*)(smc + CF_B + row * 8);
                    *(_Float16*)(smc + P2_B + ((row * 256 + col * 2) ^ SWZ(row))) =
                        (_Float16)(cc.x * (acc[mt][j] + b0s));                // partial, pre-relu
                }
            }
        }
        // ---- pass ex = 1 ----
        {
            f32x4 acc[2] = {{0,0,0,0},{0,0,0,0}};
            half8 bf = ldE2(0, 1);
            #pragma unroll
            for (int kc = 0; kc < 8; ++kc) {
                const half8 cur = bf;
                if (kc < 7) bf = ldE2(kc + 1, 1);
                const int koff = kc * 64 + kg16;
                #pragma unroll
                for (int mt = 0; mt < 2; ++mt) {
                    const int row = mt * 16 + l15;
                    const half8 af = *(const half8*)(smc + H1_B + ((row * 512 + koff) ^ SWZ(row)));
                    acc[mt] = MFMA16(af, cur, acc[mt]);
                }
            }
            MFMA_FENCE();
            __syncthreads();   // all waves' H1 reads done before H2 overlays H1 rows 0..15
            const float b1s = eb2[128 + col];
            #pragma unroll
            for (int mt = 0; mt < 2; ++mt) {
                #pragma unroll
                for (int j = 0; j < 4; ++j) {
                    const int row = mt * 16 + kgrp * 4 + j;
                    const float2 cc = *(const float2*)(smc + CF_B + row * 8);
                    const float prev = (float)*(const _Float16*)(smc + P2_B + ((row * 256 + col * 2) ^ SWZ(row)));
                    const float v = fmaxf(prev + cc.y * (acc[mt][j] + b1s), 0.f);
                    *(_Float16*)(smc + H2_B + ((row * 256 + col * 2) ^ SWZ(row))) = (_Float16)v;
                }
            }
        }
    }
    __syncthreads();

    // ---------- E3: mu = tanh(blend(H2 @ ewm[e]^T + ebm[e]))  M=32 N=17x2 K=128 ----------
    if (wv < 4) {
        const int colt = wv & 1;
        const int mtq  = wv >> 1;
        f32x4 c0a = {0,0,0,0}, c1a = {0,0,0,0};
        const int col  = colt * 16 + l15;
        const bool vcol = (col < 17);
        const int arow = mtq * 16 + l15;
        for (int kc = 0; kc < 4; ++kc) {
            const int koff = kc * 64 + kg16;
            const half8 af = *(const half8*)(smc + H2_B + ((arow * 256 + koff) ^ SWZ(arow)));
            half8 b0, b1;
            if constexpr (USE_WS) {
                b0 = *(const half8*)(wsw + WS_EM + (colt * 4 + kc) * 512 + lB);
                b1 = *(const half8*)(wsw + WS_EM + ((2 + colt) * 4 + kc) * 512 + lB);
            } else {
                const int g = kc * 4 + kgrp;
                b0 = vcol ? cvt8(ewm + col * 128 + g * 8)        : zf;
                b1 = vcol ? cvt8(ewm + (17 + col) * 128 + g * 8) : zf;
            }
            c0a = MFMA16(af, b0, c0a);
            c1a = MFMA16(af, b1, c1a);
        }
        MFMA_FENCE();
        if (vcol) {
            const float b0 = ebm[col], b1 = ebm[17 + col];
            #pragma unroll
            for (int j = 0; j < 4; ++j) {
                const int row = mtq * 16 + kgrp * 4 + j;
                const float2 cc = *(const float2*)(smc + CF_B + row * 8);
                const float z = cc.x * (c0a[j] + b0) + cc.y * (c1a[j] + b1);
                const float e2x = __expf(2.f * z);
                out[(long)(base + row) * 17 + col] = 1.f - 2.f / (e2x + 1.f);
            }
        }
    }
}

extern "C" void kernel_launch(void* const* d_in, const int* in_sizes, int n_in,
                              void* d_out, int out_size, void* d_ws, size_t ws_size,
                              hipStream_t stream) {
    (void)in_sizes; (void)n_in; (void)out_size;
    const float* states = (const float*)d_in[0];
    const float* bw1 = (const float*)d_in[1];
    const float* bb1 = (const float*)d_in[2];
    const float* bw2 = (const float*)d_in[3];
    const float* bb2 = (const float*)d_in[4];
    const float* bwo = (const float*)d_in[5];
    const float* bbo = (const float*)d_in[6];
    const float* ew1 = (const float*)d_in[7];
    const float* eb1 = (const float*)d_in[8];
    const float* ew2 = (const float*)d_in[9];
    const float* eb2 = (const float*)d_in[10];
    const float* ewm = (const float*)d_in[11];
    const float* ebm = (const float*)d_in[12];
    float* out = (float*)d_out;

    const int nblk = 65536 / MT;   // 2048

    if (d_ws != nullptr && ws_size >= (size_t)WS_BYTES) {
        _Float16* wsw = (_Float16*)d_ws;
        prep_weights<<<dim3((WS_HALFS + 255) / 256), dim3(256), 0, stream>>>(
            bw1, bb1, bw2, ew1, eb1, ew2, ewm, wsw);
        actor_kernel<true><<<dim3(nblk), dim3(T), LDS_BYTES, stream>>>(
            states, bw1, bb1, bw2, bb2, bwo, bbo,
            ew1, eb1, ew2, eb2, ewm, ebm, wsw, out);
    } else {
        actor_kernel<false><<<dim3(nblk), dim3(T), LDS_BYTES, stream>>>(
            states, bw1, bb1, bw2, bb2, bwo, bbo,
            ew1, eb1, ew2, eb2, ewm, ebm, nullptr, out);
    }
}

// Round 26
// 84.058 us; speedup vs baseline: 1.4903x; 1.4903x over previous
//
#include <hip/hip_runtime.h>
#include <math.h>

// Fused Actor network via single-term fp16 MFMA. FINAL (= round 18, session best 84.2us).
// B=65536: blending 376->128->128->2 softmax; experts 376->256->128->17 blended, tanh.
// 31x vs fp32 baseline (2614us). Structure: block = 32 samples, 512 threads = 8 waves,
// LDS 41,216B -> 2 blocks/CU (4 waves/SIMD); fp16 MFMA 16x16x32 via intrinsic (the
// 64-AGPR granule costs nothing at this occupancy and avoids asm fence overhead).
// Counter-proven facts from the 25-round session:
//  - occupancy frontier closed: 3 blocks/CU needs <=40 regs (unreachable, demand ~51);
//    spill-free needs >=51 regs (caps at 2 blocks/CU). r18's busy% ~= occupancy% with
//    zero spills = the fixed point of this barrier-phased fused structure.
//  - L2 weight-stream BW not binding (halving it changed nothing, r17).
//  - depth-2 prefetch / pre-issue neutral or harmful (r13/r18).
// Techniques: weights pre-tiled in d_ws as MFMA B-fragment tiles (per-wave 1KB bursts);
// bias folded into K-pad col 376 (S col=1.0) for A1/E1; coeffs f32 in CF; fast tanh;
// LDS XOR-swizzle byte^=(row&7)<<4; E1 split into two 16-col passes (16 accs live).

typedef __attribute__((ext_vector_type(8))) _Float16 half8;
typedef __attribute__((ext_vector_type(4))) _Float16 half4;
typedef __attribute__((ext_vector_type(4))) float    f32x4;

#define MFMA16(a, b, c) __builtin_amdgcn_mfma_f32_16x16x32_f16((a), (b), (c), 0, 0, 0)
#define SWZ(row) (((row) & 7) << 4)

#define MT 32
#define T  512

// ---- LDS byte offsets (total 41,216 B) ----
// S  [0, 24576): 32 rows x 384 f16 (stride 768B); col376 = 1.0 (bias), 377..383 = 0.
// G1 [24576, 32768): 32x128 f16 (stride 256B)
// G2 [32768, 40960): 32x128 f16
// H1 [24576, 40960): 32x256 f16 (stride 512B), overlays G1+G2 (dead after A3)
// H2 [24576, 32768): 32x128 f16, overlays H1 low half (barrier inside E2)
// CF [40960, 41216): 32 x (c0,c1) f32
#define S_B      0
#define G1_B     24576
#define G2_B     32768
#define H1_B     24576
#define H2_B     24576
#define CF_B     40960
#define LDS_BYTES 41216

// ---- ws half-element offsets; tiled: tile(n0,kc) at ((n0*KC+kc)*512), [lane][8] ----
#define WS_W1 0        /* bw1: N0=8,  KC=12 (k=376 holds bb1) */
#define WS_W2 49152    /* bw2: N0=8,  KC=4 */
#define WS_E1 65536    /* ew1: N0=32, KC=12 (k=376 holds eb1) */
#define WS_E2 262144   /* ew2: N0=16, KC=8 */
#define WS_EM 327680   /* ewm: N0=4,  KC=4 (2 experts x 32 rows padded) */
#define WS_HALFS 335872
#define WS_BYTES 671744

__device__ __forceinline__ half8 cvt8(const float* __restrict__ p) {
    const float4 a = *reinterpret_cast<const float4*>(p);
    const float4 b = *reinterpret_cast<const float4*>(p + 4);
    half8 r;
    r[0] = (_Float16)a.x; r[1] = (_Float16)a.y; r[2] = (_Float16)a.z; r[3] = (_Float16)a.w;
    r[4] = (_Float16)b.x; r[5] = (_Float16)b.y; r[6] = (_Float16)b.z; r[7] = (_Float16)b.w;
    return r;
}

// ================= prep kernel: fp32 weights -> fp16 B-fragment tiles in ws =================
__global__ __launch_bounds__(256)
void prep_weights(const float* __restrict__ bw1, const float* __restrict__ bb1,
                  const float* __restrict__ bw2,
                  const float* __restrict__ ew1, const float* __restrict__ eb1,
                  const float* __restrict__ ew2,
                  const float* __restrict__ ewm, _Float16* __restrict__ wsw)
{
    const int i = blockIdx.x * 256 + threadIdx.x;
    if (i >= WS_HALFS) return;
    int sec; const float* W; const float* Bv; int N, K, KC, j0;
    if      (i < 49152)  { sec = 0; W = bw1; Bv = bb1;     N = 128; K = 376; KC = 12; j0 = i - WS_W1; }
    else if (i < 65536)  { sec = 1; W = bw2; Bv = nullptr; N = 128; K = 128; KC = 4;  j0 = i - WS_W2; }
    else if (i < 262144) { sec = 2; W = ew1; Bv = eb1;     N = 512; K = 376; KC = 12; j0 = i - WS_E1; }
    else if (i < 327680) { sec = 3; W = ew2; Bv = nullptr; N = 256; K = 256; KC = 8;  j0 = i - WS_E2; }
    else                 { sec = 4; W = ewm; Bv = nullptr; N = 34;  K = 128; KC = 4;  j0 = i - WS_EM; }
    const int tile = j0 >> 9;
    const int rem  = j0 & 511;
    const int l    = rem >> 3;
    const int jj   = rem & 7;
    const int n0   = tile / KC, kc = tile - n0 * KC;
    const int n = n0 * 16 + (l & 15);
    const int k = kc * 32 + (l >> 4) * 8 + jj;
    float v = 0.f;
    if (sec == 4) {
        const int e = n >> 5, a = n & 31;
        if (a < 17 && k < K) v = ewm[(e * 17 + a) * K + k];
    } else if (n < N) {
        if (k < K)             v = W[n * K + k];
        else if (k == K && Bv) v = Bv[n];
    }
    wsw[i] = (_Float16)v;
}

// ================= fused actor kernel =================
template <bool USE_WS>
__global__ __launch_bounds__(512)
__attribute__((amdgpu_waves_per_eu(2)))
void actor_kernel(const float* __restrict__ states,
                  const float* __restrict__ bw1, const float* __restrict__ bb1,
                  const float* __restrict__ bw2, const float* __restrict__ bb2,
                  const float* __restrict__ bwo, const float* __restrict__ bbo,
                  const float* __restrict__ ew1, const float* __restrict__ eb1,
                  const float* __restrict__ ew2, const float* __restrict__ eb2,
                  const float* __restrict__ ewm, const float* __restrict__ ebm,
                  const _Float16* __restrict__ wsw,
                  float* __restrict__ out)
{
    extern __shared__ char smc[];
    const int t    = threadIdx.x;
    const int l    = t & 63;
    const int l15  = l & 15;
    const int kgrp = l >> 4;
    const int kg16 = kgrp * 16;
    const int wv   = __builtin_amdgcn_readfirstlane(t >> 6);
    const int base = blockIdx.x * MT;
    const int lB   = l * 8;

    const half8 zf = {0,0,0,0,0,0,0,0};

    // ---------- stage ----------
    {
        const float4* src = reinterpret_cast<const float4*>(states + (long)base * 376);
        for (int q = t; q < MT * 94; q += T) {
            const int r  = q / 94;
            const int c4 = q - r * 94;
            const float4 v = src[q];
            half4 h;
            h[0] = (_Float16)v.x; h[1] = (_Float16)v.y;
            h[2] = (_Float16)v.z; h[3] = (_Float16)v.w;
            *(half4*)(smc + S_B + ((r * 768 + c4 * 8) ^ SWZ(r))) = h;
        }
        if (t < MT) {
            const int off = (t * 768 + 752) ^ SWZ(t);
            *(ushort4*)(smc + S_B + off)     = make_ushort4(0x3C00u, 0, 0, 0);
            *(ushort4*)(smc + S_B + off + 8) = make_ushort4(0, 0, 0, 0);
        }
    }
    __syncthreads();

    // ---------- A1: G1 = relu(S @ bw1^T [+bb1 via pad])  M=32 N=128 K=384 ----------
    {
        f32x4 acc[2] = {{0,0,0,0},{0,0,0,0}};
        const int col = wv * 16 + l15;
        auto ldW = [&](int kc) -> half8 {
            if constexpr (USE_WS) return *(const half8*)(wsw + WS_W1 + (wv * 12 + kc) * 512 + lB);
            else {
                const int g = kc * 4 + kgrp;
                if (g < 47) return cvt8(bw1 + col * 376 + g * 8);
                half8 rr = zf; rr[0] = (_Float16)bb1[col]; return rr;
            }
        };
        half8 bq[2] = { ldW(0), ldW(1) };
        #pragma unroll
        for (int kc = 0; kc < 12; ++kc) {
            const half8 cur = bq[kc & 1];
            if (kc + 2 < 12) bq[kc & 1] = ldW(kc + 2);
            const int koff = kc * 64 + kg16;
            #pragma unroll
            for (int mt = 0; mt < 2; ++mt) {
                const int row = mt * 16 + l15;
                const half8 af = *(const half8*)(smc + S_B + ((row * 768 + koff) ^ SWZ(row)));
                acc[mt] = MFMA16(af, cur, acc[mt]);
            }
        }
        #pragma unroll
        for (int mt = 0; mt < 2; ++mt) {
            #pragma unroll
            for (int j = 0; j < 4; ++j) {
                const int row = mt * 16 + kgrp * 4 + j;
                const float v = fmaxf(acc[mt][j], 0.f);   // bias in acc
                *(_Float16*)(smc + G1_B + ((row * 256 + col * 2) ^ SWZ(row))) = (_Float16)v;
            }
        }
    }
    __syncthreads();

    // ---------- A2: G2 = relu(G1 @ bw2^T + bb2)  M=32 N=128 K=128 ----------
    {
        f32x4 acc[2] = {{0,0,0,0},{0,0,0,0}};
        const int col = wv * 16 + l15;
        auto ldW = [&](int kc) -> half8 {
            if constexpr (USE_WS) return *(const half8*)(wsw + WS_W2 + (wv * 4 + kc) * 512 + lB);
            else                  return cvt8(bw2 + col * 128 + (kc * 4 + kgrp) * 8);
        };
        half8 bq[2] = { ldW(0), ldW(1) };
        #pragma unroll
        for (int kc = 0; kc < 4; ++kc) {
            const half8 cur = bq[kc & 1];
            if (kc + 2 < 4) bq[kc & 1] = ldW(kc + 2);
            const int koff = kc * 64 + kg16;
            #pragma unroll
            for (int mt = 0; mt < 2; ++mt) {
                const int row = mt * 16 + l15;
                const half8 af = *(const half8*)(smc + G1_B + ((row * 256 + koff) ^ SWZ(row)));
                acc[mt] = MFMA16(af, cur, acc[mt]);
            }
        }
        const float bias = bb2[col];
        #pragma unroll
        for (int mt = 0; mt < 2; ++mt) {
            #pragma unroll
            for (int j = 0; j < 4; ++j) {
                const int row = mt * 16 + kgrp * 4 + j;
                const float v = fmaxf(acc[mt][j] + bias, 0.f);
                *(_Float16*)(smc + G2_B + ((row * 256 + col * 2) ^ SWZ(row))) = (_Float16)v;
            }
        }
    }
    __syncthreads();

    // ---------- A3: softmax coeffs -> f32 (c0,c1) in CF ----------
    {
        const int s     = t >> 4;
        const int r     = t & 15;
        const int e     = r & 1;
        const int chunk = r >> 1;
        float z = 0.f;
        const float* wo = bwo + e * 128 + chunk * 16;
        #pragma unroll
        for (int q = 0; q < 2; ++q) {
            const half8 hv = *(const half8*)(smc + G2_B + ((s * 256 + chunk * 32 + q * 16) ^ SWZ(s)));
            const float4 w0 = *(const float4*)(wo + q * 8);
            const float4 w1 = *(const float4*)(wo + q * 8 + 4);
            z = fmaf((float)hv[0], w0.x, z); z = fmaf((float)hv[1], w0.y, z);
            z = fmaf((float)hv[2], w0.z, z); z = fmaf((float)hv[3], w0.w, z);
            z = fmaf((float)hv[4], w1.x, z); z = fmaf((float)hv[5], w1.y, z);
            z = fmaf((float)hv[6], w1.z, z); z = fmaf((float)hv[7], w1.w, z);
        }
        z += __shfl_xor(z, 2, 64);
        z += __shfl_xor(z, 4, 64);
        z += __shfl_xor(z, 8, 64);
        z += bbo[e];
        const float zo = __shfl_xor(z, 1, 64);
        if (r < 2) {
            const float m = fmaxf(z, zo);
            const float ea = __expf(z - m), eb = __expf(zo - m);
            *(float*)(smc + CF_B + s * 8 + e * 4) = ea / (ea + eb);
        }
    }
    __syncthreads();

    // ---------- E1: H1 = relu(blend(S @ ew1[e]^T [+eb1 via pad]))  M=32 N=256x2 K=384 ----------
    // Two sequential passes (16 cols each): 2 weight streams x depth-2, 16 accs live.
    #pragma unroll 1
    for (int p = 0; p < 2; ++p) {
        f32x4 aA[2], aB[2];
        #pragma unroll
        for (int mt = 0; mt < 2; ++mt) { aA[mt] = {0,0,0,0}; aB[mt] = {0,0,0,0}; }
        auto ldE1 = [&](int kc, int ex) -> half8 {
            if constexpr (USE_WS) {
                const int n0 = wv * 2 + p + ex * 16;
                return *(const half8*)(wsw + WS_E1 + (n0 * 12 + kc) * 512 + lB);
            } else {
                const int g = kc * 4 + kgrp;
                const int wr = wv * 32 + p * 16 + l15 + ex * 256;
                if (g < 47) return cvt8(ew1 + wr * 376 + g * 8);
                half8 rr = zf; rr[0] = (_Float16)eb1[wr]; return rr;
            }
        };
        half8 b0q[2] = { ldE1(0, 0), ldE1(1, 0) };
        half8 b1q[2] = { ldE1(0, 1), ldE1(1, 1) };
        #pragma unroll
        for (int kc = 0; kc < 12; ++kc) {
            const half8 c0f = b0q[kc & 1], c1f = b1q[kc & 1];
            if (kc + 2 < 12) { b0q[kc & 1] = ldE1(kc + 2, 0); b1q[kc & 1] = ldE1(kc + 2, 1); }
            const int koff = kc * 64 + kg16;
            #pragma unroll
            for (int mt = 0; mt < 2; ++mt) {
                const int row = mt * 16 + l15;
                const half8 af = *(const half8*)(smc + S_B + ((row * 768 + koff) ^ SWZ(row)));
                aA[mt] = MFMA16(af, c0f, aA[mt]);
                aB[mt] = MFMA16(af, c1f, aB[mt]);
            }
        }
        const int col = wv * 32 + p * 16 + l15;
        #pragma unroll
        for (int mt = 0; mt < 2; ++mt) {
            #pragma unroll
            for (int j = 0; j < 4; ++j) {
                const int row = mt * 16 + kgrp * 4 + j;
                const float2 cc = *(const float2*)(smc + CF_B + row * 8);
                const float v = fmaxf(cc.x * aA[mt][j] + cc.y * aB[mt][j], 0.f);  // bias in acc
                *(_Float16*)(smc + H1_B + ((row * 512 + col * 2) ^ SWZ(row))) = (_Float16)v;
            }
        }
    }
    __syncthreads();

    // ---------- E2: H2 = relu(blend(H1 @ ew2[e]^T + eb2[e]))  M=32 N=128x2 K=256 ----------
    {
        f32x4 cA[2], cB[2];
        #pragma unroll
        for (int mt = 0; mt < 2; ++mt) { cA[mt] = {0,0,0,0}; cB[mt] = {0,0,0,0}; }
        const int col = wv * 16 + l15;
        auto ldE2 = [&](int kc, int ex) -> half8 {
            if constexpr (USE_WS) {
                return *(const half8*)(wsw + WS_E2 + ((wv + ex * 8) * 8 + kc) * 512 + lB);
            } else {
                const int g = kc * 4 + kgrp;
                return cvt8(ew2 + (col + ex * 128) * 256 + g * 8);
            }
        };
        half8 b0q[2] = { ldE2(0, 0), ldE2(1, 0) };
        half8 b1q[2] = { ldE2(0, 1), ldE2(1, 1) };
        #pragma unroll
        for (int kc = 0; kc < 8; ++kc) {
            const half8 c0f = b0q[kc & 1], c1f = b1q[kc & 1];
            if (kc + 2 < 8) { b0q[kc & 1] = ldE2(kc + 2, 0); b1q[kc & 1] = ldE2(kc + 2, 1); }
            const int koff = kc * 64 + kg16;
            #pragma unroll
            for (int mt = 0; mt < 2; ++mt) {
                const int row = mt * 16 + l15;
                const half8 af = *(const half8*)(smc + H1_B + ((row * 512 + koff) ^ SWZ(row)));
                cA[mt] = MFMA16(af, c0f, cA[mt]);
                cB[mt] = MFMA16(af, c1f, cB[mt]);
            }
        }
        __syncthreads();   // all H1 reads done before H2 overlays H1 low half
        const float b0s = eb2[col], b1s = eb2[128 + col];
        #pragma unroll
        for (int mt = 0; mt < 2; ++mt) {
            #pragma unroll
            for (int j = 0; j < 4; ++j) {
                const int row = mt * 16 + kgrp * 4 + j;
                const float2 cc = *(const float2*)(smc + CF_B + row * 8);
                const float v = fmaxf(cc.x * (cA[mt][j] + b0s) + cc.y * (cB[mt][j] + b1s), 0.f);
                *(_Float16*)(smc + H2_B + ((row * 256 + col * 2) ^ SWZ(row))) = (_Float16)v;
            }
        }
    }
    __syncthreads();

    // ---------- E3: mu = tanh(blend(H2 @ ewm[e]^T + ebm[e]))  M=32 N=17x2 K=128 ----------
    if (wv < 4) {
        const int colt = wv & 1;
        const int mtq  = wv >> 1;
        f32x4 c0a = {0,0,0,0}, c1a = {0,0,0,0};
        const int col  = colt * 16 + l15;
        const bool vcol = (col < 17);
        const int arow = mtq * 16 + l15;
        for (int kc = 0; kc < 4; ++kc) {
            const int koff = kc * 64 + kg16;
            const half8 af = *(const half8*)(smc + H2_B + ((arow * 256 + koff) ^ SWZ(arow)));
            half8 b0, b1;
            if constexpr (USE_WS) {
                b0 = *(const half8*)(wsw + WS_EM + (colt * 4 + kc) * 512 + lB);
                b1 = *(const half8*)(wsw + WS_EM + ((2 + colt) * 4 + kc) * 512 + lB);
            } else {
                const int g = kc * 4 + kgrp;
                b0 = vcol ? cvt8(ewm + col * 128 + g * 8)        : zf;
                b1 = vcol ? cvt8(ewm + (17 + col) * 128 + g * 8) : zf;
            }
            c0a = MFMA16(af, b0, c0a);
            c1a = MFMA16(af, b1, c1a);
        }
        if (vcol) {
            const float b0 = ebm[col], b1 = ebm[17 + col];
            #pragma unroll
            for (int j = 0; j < 4; ++j) {
                const int row = mtq * 16 + kgrp * 4 + j;
                const float2 cc = *(const float2*)(smc + CF_B + row * 8);
                const float z = cc.x * (c0a[j] + b0) + cc.y * (c1a[j] + b1);
                const float e2x = __expf(2.f * z);
                out[(long)(base + row) * 17 + col] = 1.f - 2.f / (e2x + 1.f);
            }
        }
    }
}

extern "C" void kernel_launch(void* const* d_in, const int* in_sizes, int n_in,
                              void* d_out, int out_size, void* d_ws, size_t ws_size,
                              hipStream_t stream) {
    (void)in_sizes; (void)n_in; (void)out_size;
    const float* states = (const float*)d_in[0];
    const float* bw1 = (const float*)d_in[1];
    const float* bb1 = (const float*)d_in[2];
    const float* bw2 = (const float*)d_in[3];
    const float* bb2 = (const float*)d_in[4];
    const float* bwo = (const float*)d_in[5];
    const float* bbo = (const float*)d_in[6];
    const float* ew1 = (const float*)d_in[7];
    const float* eb1 = (const float*)d_in[8];
    const float* ew2 = (const float*)d_in[9];
    const float* eb2 = (const float*)d_in[10];
    const float* ewm = (const float*)d_in[11];
    const float* ebm = (const float*)d_in[12];
    float* out = (float*)d_out;

    const int nblk = 65536 / MT;   // 2048

    if (d_ws != nullptr && ws_size >= (size_t)WS_BYTES) {
        _Float16* wsw = (_Float16*)d_ws;
        prep_weights<<<dim3((WS_HALFS + 255) / 256), dim3(256), 0, stream>>>(
            bw1, bb1, bw2, ew1, eb1, ew2, ewm, wsw);
        actor_kernel<true><<<dim3(nblk), dim3(T), LDS_BYTES, stream>>>(
            states, bw1, bb1, bw2, bb2, bwo, bbo,
            ew1, eb1, ew2, eb2, ewm, ebm, wsw, out);
    } else {
        actor_kernel<false><<<dim3(nblk), dim3(T), LDS_BYTES, stream>>>(
            states, bw1, bb1, bw2, bb2, bwo, bbo,
            ew1, eb1, ew2, eb2, ewm, ebm, nullptr, out);
    }
}